// Round 17
// baseline (487.235 us; speedup 1.0000x reference)
//
#include <hip/hip_runtime.h>
#include <stdint.h>

typedef __attribute__((ext_vector_type(8))) short bf16x8;
typedef __attribute__((ext_vector_type(4))) float f32x4;

__device__ __forceinline__ float bf2f(ushort h) {
    union { uint u; float f; } v; v.u = ((uint)h) << 16; return v.f;
}
__device__ __forceinline__ ushort f2bf(float f) {
    union { float f; uint u; } v; v.f = f;
    uint u = v.u;
    return (ushort)((u + 0x7fffu + ((u >> 16) & 1u)) >> 16);
}

// async global->LDS, 16B per lane; LDS dest = wave-uniform base + lane*16
__device__ __forceinline__ void gll(const ushort* g, ushort* l) {
    __builtin_amdgcn_global_load_lds(
        (const __attribute__((address_space(1))) void*)g,
        (__attribute__((address_space(3))) void*)l, 16, 0, 0);
}

template <int VEC>
__device__ __forceinline__ void ldbf(const ushort* p, float* v) {
    if constexpr (VEC == 4) {
        uint2 u = *(const uint2*)p;
        v[0] = bf2f((ushort)(u.x & 0xffffu));
        v[1] = bf2f((ushort)(u.x >> 16));
        v[2] = bf2f((ushort)(u.y & 0xffffu));
        v[3] = bf2f((ushort)(u.y >> 16));
    } else {  // VEC == 8
        uint4 u = *(const uint4*)p;
        v[0] = bf2f((ushort)(u.x & 0xffffu));
        v[1] = bf2f((ushort)(u.x >> 16));
        v[2] = bf2f((ushort)(u.y & 0xffffu));
        v[3] = bf2f((ushort)(u.y >> 16));
        v[4] = bf2f((ushort)(u.z & 0xffffu));
        v[5] = bf2f((ushort)(u.z >> 16));
        v[6] = bf2f((ushort)(u.w & 0xffffu));
        v[7] = bf2f((ushort)(u.w >> 16));
    }
}

// ---------------- merged init: prep (classify + x->bf16) | deg | weight split ----------------
// NOTE: no gcnt atomics here (r12: 12.5k blocks on one cacheline cost +100us).

__device__ __forceinline__ void tr2_one(const float* __restrict__ W,
                                        ushort* __restrict__ WTh, ushort* __restrict__ WTl,
                                        int K, int Nc, int KP, int idx) {
    int n = idx / KP, k = idx % KP;
    float w = (n < Nc && k < K) ? W[(size_t)k * Nc + n] : 0.0f;
    ushort hi = f2bf(w);
    ushort lo = f2bf(w - bf2f(hi));
    WTh[idx] = hi;
    WTl[idx] = lo;
}

__global__ void k_init(const uint* __restrict__ xu, const uint* __restrict__ nfu,
                       ushort* __restrict__ xb, int* __restrict__ gid, int NN,
                       const int* __restrict__ dst, int E, int* __restrict__ deg,
                       const float* __restrict__ W1, const float* __restrict__ W2,
                       const float* __restrict__ W3, const float* __restrict__ W4,
                       ushort* __restrict__ WT1h, ushort* __restrict__ WT1l,
                       ushort* __restrict__ WT2h, ushort* __restrict__ WT2l,
                       ushort* __restrict__ WT3h, ushort* __restrict__ WT3l,
                       ushort* __restrict__ WT4h, ushort* __restrict__ WT4l,
                       int PB, int EB) {
    int b = blockIdx.x;
    if (b < PB) {
        int wid = b * 4 + (threadIdx.x >> 6);
        int lane = threadIdx.x & 63;
        if (wid >= NN) return;
        int c0 = lane * 2;
        uint w = 0u;
        int m0 = 1, m1 = 1, m2 = 1;
        if (c0 < 100) {
            uint2 xv = *(const uint2*)&xu[(size_t)wid * 100 + c0];
            uint2 a = *(const uint2*)&nfu[c0];
            uint2 bb = *(const uint2*)&nfu[100 + c0];
            uint2 c = *(const uint2*)&nfu[200 + c0];
            m0 = (xv.x == a.x) & (xv.y == a.y);
            m1 = (xv.x == bb.x) & (xv.y == bb.y);
            m2 = (xv.x == c.x) & (xv.y == c.y);
            w = (uint)f2bf(__uint_as_float(xv.x)) | ((uint)f2bf(__uint_as_float(xv.y)) << 16);
        }
        int e0 = __all(m0), e1 = __all(m1), e2 = __all(m2);
        *(uint*)&xb[(size_t)wid * 128 + c0] = w;
        if (lane == 0) gid[wid] = e0 ? 0 : (e1 ? 3 : (e2 ? 1 : 2));
    } else if (b < PB + EB) {
        int e = (b - PB) * 256 + threadIdx.x;
        if (e < E) atomicAdd(&deg[dst[e]], 1);
    } else {
        int idx = (b - PB - EB) * 256 + threadIdx.x;
        if (idx < 65536) tr2_one(W1, WT1h, WT1l, 100, 512, 128, idx);
        else if (idx < 196608) tr2_one(W2, WT2h, WT2l, 512, 256, 512, idx - 65536);
        else if (idx < 229376) tr2_one(W3, WT3h, WT3l, 256, 128, 256, idx - 196608);
        else if (idx < 262144) tr2_one(W4, WT4h, WT4l, 128, 200, 128, idx - 229376);
    }
}

// ---------------- scanA: block-local prefix + dinv + group counts ----------------
// (196 blocks x 4 gcnt atomics ~ 1.6us; safe per r12 scaling, unlike 12.5k blocks)

__global__ void k_scanA(const int* __restrict__ deg, int* __restrict__ offs,
                        int* __restrict__ bsum, float* __restrict__ dinv,
                        const int* __restrict__ gid, int* __restrict__ gcnt, int NN) {
    __shared__ int lds[256];
    __shared__ int cnt4[4];
    int t = threadIdx.x;
    if (t < 4) cnt4[t] = 0;
    int i = blockIdx.x * 256 + t;
    int v = (i < NN) ? deg[i] : 0;
    if (i < NN) {
        dinv[i] = 1.0f / sqrtf((float)(v + 1));  // +1 self loop
    }
    lds[t] = v;
    __syncthreads();
    if (i < NN) atomicAdd(&cnt4[gid[i]], 1);
    for (int d = 1; d < 256; d <<= 1) {
        int u = (t >= d) ? lds[t - d] : 0;
        __syncthreads();
        lds[t] += u;
        __syncthreads();
    }
    if (i < NN) offs[i] = lds[t] - v;  // block-local exclusive
    if (t == 255) bsum[blockIdx.x] = lds[255];
    __syncthreads();
    if (t < 4 && cnt4[t]) atomicAdd(&gcnt[t], cnt4[t]);
}

// ---------------- fill: recompute bsum prefix in-block (kills scanB launch) ----------------
// offs[] holds block-local exclusive prefix; global base = excl-prefix of bsum.

__global__ void k_fill(const int* __restrict__ src, const int* __restrict__ dst, int E,
                       const float* __restrict__ dinv, const int* __restrict__ offs,
                       const int* __restrict__ bsum,
                       int* __restrict__ cur, uint2* __restrict__ epk, int NN, int NB,
                       int* __restrict__ goffs) {
    __shared__ int sex[256];
    int t = threadIdx.x;
    int v = (t < NB) ? bsum[t] : 0;
    sex[t] = v;
    __syncthreads();
    for (int d = 1; d < 256; d <<= 1) {
        int u = (t >= d) ? sex[t - d] : 0;
        __syncthreads();
        sex[t] += u;
        __syncthreads();
    }
    int incl = sex[t];
    __syncthreads();
    sex[t] = incl - v;  // exclusive prefix of bsum
    __syncthreads();
    int i = blockIdx.x * 256 + t;
    if (i < NN) goffs[i] = offs[i] + sex[i >> 8];
    if (i >= E) return;
    int s = src[i], d = dst[i];
    int p = offs[d] + sex[d >> 8] + atomicAdd(&cur[d], 1);
    epk[p] = make_uint2((uint)s, __float_as_uint(dinv[s] * dinv[d]));
}

// ---------------- aggregation: wave per node, edge-split across half-waves ----------------

template <int D, bool BR>
__global__ void k_aggs(const ushort* __restrict__ H, ushort* __restrict__ outb,
                       const float* __restrict__ dinv, const int* __restrict__ offs,
                       const int* __restrict__ deg, const uint2* __restrict__ epk,
                       const float* __restrict__ bias, int NN, int NNpad) {
    constexpr int VEC = D / 32;  // cols per lane (half-wave covers the row)
    int wid = (int)((blockIdx.x * blockDim.x + threadIdx.x) >> 6);
    int lane = threadIdx.x & 63;
    int half = lane >> 5, sl = lane & 31;
    if (wid >= NNpad) return;
    int c0 = sl * VEC;
    ushort* op = outb + (size_t)wid * D + c0;
    if (wid >= NN) {  // zero pad rows
        if (half == 0) {
            if (VEC == 4) *(uint2*)op = make_uint2(0u, 0u);
            else { uint4 z; z.x = z.y = z.z = z.w = 0u; *(uint4*)op = z; }
        }
        return;
    }
    float acc[VEC];
#pragma unroll
    for (int j = 0; j < VEC; ++j) acc[j] = 0.0f;
    int beg = offs[wid], d = deg[wid];
    if (half == 0) {  // self-loop term on half 0
        float t0[VEC];
        ldbf<VEC>(H + (size_t)wid * D + c0, t0);
        float di = dinv[wid];
        float sw = di * di;
#pragma unroll
        for (int j = 0; j < VEC; ++j) acc[j] = sw * t0[j];
    }
    int d0 = (d + 1) >> 1;
    int e = beg + half * d0;
    int end = e + (half ? (d - d0) : d0);
    for (; e + 3 < end; e += 4) {
        uint2 q0 = epk[e], q1 = epk[e + 1], q2 = epk[e + 2], q3 = epk[e + 3];
        float t0[VEC], t1[VEC], t2[VEC], t3[VEC];
        ldbf<VEC>(H + (size_t)q0.x * D + c0, t0);
        ldbf<VEC>(H + (size_t)q1.x * D + c0, t1);
        ldbf<VEC>(H + (size_t)q2.x * D + c0, t2);
        ldbf<VEC>(H + (size_t)q3.x * D + c0, t3);
        float w0 = __uint_as_float(q0.y), w1 = __uint_as_float(q1.y);
        float w2 = __uint_as_float(q2.y), w3 = __uint_as_float(q3.y);
#pragma unroll
        for (int j = 0; j < VEC; ++j) acc[j] += w0 * t0[j];
#pragma unroll
        for (int j = 0; j < VEC; ++j) acc[j] += w1 * t1[j];
#pragma unroll
        for (int j = 0; j < VEC; ++j) acc[j] += w2 * t2[j];
#pragma unroll
        for (int j = 0; j < VEC; ++j) acc[j] += w3 * t3[j];
    }
    for (; e < end; ++e) {
        uint2 q0 = epk[e];
        float t0[VEC];
        ldbf<VEC>(H + (size_t)q0.x * D + c0, t0);
        float w0 = __uint_as_float(q0.y);
#pragma unroll
        for (int j = 0; j < VEC; ++j) acc[j] += w0 * t0[j];
    }
#pragma unroll
    for (int j = 0; j < VEC; ++j) acc[j] += __shfl_xor(acc[j], 32);
    if (half == 0) {
        ushort r[VEC];
#pragma unroll
        for (int j = 0; j < VEC; ++j) {
            float v = acc[j];
            if (BR) v = fmaxf(v + bias[c0 + j], 0.0f);
            r[j] = f2bf(v);
        }
        if (VEC == 4) {
            uint2 w;
            w.x = (uint)r[0] | ((uint)r[1] << 16);
            w.y = (uint)r[2] | ((uint)r[3] << 16);
            *(uint2*)op = w;
        } else {
            uint4 w;
            w.x = (uint)r[0] | ((uint)r[1] << 16);
            w.y = (uint)r[2] | ((uint)r[3] << 16);
            w.z = (uint)r[4] | ((uint)r[5] << 16);
            w.w = (uint)r[6] | ((uint)r[7] << 16);
            *(uint4*)op = w;
        }
    }
}

// ---------------- MFMA GEMM: A bf16 single plane, W hi/lo split (2-term) ----------------
// Block tile 128x128, 4 waves (64x64). OUT: 1 = bf16 store,
// 2 = fused per-group reduction into gsum + last-block final divide (no k_final).

template <bool BR, int OUT>
__global__ __launch_bounds__(256) void k_gemm(
        const ushort* __restrict__ A,
        const ushort* __restrict__ Bh, const ushort* __restrict__ Bl,
        const float* __restrict__ bias,
        ushort* __restrict__ Cb,
        int Nc, int K, int tNb,
        const int* __restrict__ gid, float* __restrict__ gsum, int NN,
        int* __restrict__ gcnt, float* __restrict__ outF, int* __restrict__ donecnt) {
    __shared__ union {
        ushort st[3][128 * 32];
        float epi[64 * 132];
    } sm;
    __shared__ int gcode[64];
    __shared__ int lastFlag;
    int bm = blockIdx.x / tNb, bn = blockIdx.x % tNb;
    int m0 = bm * 128, n0 = bn * 128;
    int wv = threadIdx.x >> 6, lane = threadIdx.x & 63;
    int l15 = lane & 15, quad = lane >> 4;
    const ushort* gsrc;
    ushort* ldst;
    int ng;
    if (wv == 0)      { gsrc = A  + (size_t)m0 * K;        ldst = sm.st[0];        ng = 4; }
    else if (wv == 1) { gsrc = A  + (size_t)(m0 + 64) * K; ldst = sm.st[0] + 2048; ng = 4; }
    else if (wv == 2) { gsrc = Bh + (size_t)n0 * K;        ldst = sm.st[1];        ng = 8; }
    else              { gsrc = Bl + (size_t)n0 * K;        ldst = sm.st[2];        ng = 8; }
    const ushort* gBase = gsrc + (size_t)(lane >> 2) * K + (lane & 3) * 8;
    int wm = (wv >> 1) * 64, wn = (wv & 1) * 64;
    const ushort* sA_ = sm.st[0];
    const ushort* sBh_ = sm.st[1];
    const ushort* sBl_ = sm.st[2];
    f32x4 acc[4][4] = {};
    for (int k0 = 0; k0 < K; k0 += 32) {
        for (int i = 0; i < ng; ++i)
            gll(gBase + (size_t)(16 * i) * K + k0, ldst + i * 512);
        __syncthreads();
        bf16x8 Af[4], Bfh[4], Bfl[4];
#pragma unroll
        for (int i = 0; i < 4; ++i) {
            int ra = (wm + 16 * i + l15) * 32 + quad * 8;
            int rb = (wn + 16 * i + l15) * 32 + quad * 8;
            Af[i]  = *(const bf16x8*)(sA_ + ra);
            Bfh[i] = *(const bf16x8*)(sBh_ + rb);
            Bfl[i] = *(const bf16x8*)(sBl_ + rb);
        }
#pragma unroll
        for (int mi = 0; mi < 4; ++mi)
#pragma unroll
            for (int ni = 0; ni < 4; ++ni) {
                acc[mi][ni] = __builtin_amdgcn_mfma_f32_16x16x32_bf16(Af[mi], Bfh[ni], acc[mi][ni], 0, 0, 0);
                acc[mi][ni] = __builtin_amdgcn_mfma_f32_16x16x32_bf16(Af[mi], Bfl[ni], acc[mi][ni], 0, 0, 0);
            }
        __syncthreads();
    }
    float bia[4] = {0.f, 0.f, 0.f, 0.f};
    if (BR) {
#pragma unroll
        for (int ni = 0; ni < 4; ++ni) {
            int col = n0 + wn + 16 * ni + l15;
            if (col < Nc) bia[ni] = bias[col];
        }
    }
    float* epi = sm.epi;
    int t = threadIdx.x;
    float s0 = 0.f, s1 = 0.f, s2 = 0.f, s3 = 0.f;  // OUT==2 per-group sums
    int colR = t & 127, rg = t >> 7;
    for (int half = 0; half < 2; ++half) {
        if ((wv >> 1) == half) {
#pragma unroll
            for (int mi = 0; mi < 4; ++mi)
#pragma unroll
                for (int r = 0; r < 4; ++r) {
                    int rl = mi * 16 + quad * 4 + r;
#pragma unroll
                    for (int ni = 0; ni < 4; ++ni) {
                        float v = acc[mi][ni][r];
                        if (BR) v = fmaxf(v + bia[ni], 0.0f);
                        epi[rl * 132 + wn + ni * 16 + l15] = v;
                    }
                }
        }
        if (OUT == 2 && t < 64) {
            int grow = m0 + half * 64 + t;
            gcode[t] = (grow < NN) ? gid[grow] : -1;
        }
        __syncthreads();
        if (OUT == 2) {
#pragma unroll 4
            for (int r = 0; r < 32; ++r) {
                int row = rg * 32 + r;
                int g = gcode[row];
                float v = epi[row * 132 + colR];
                s0 += (g == 0) ? v : 0.f;
                s1 += (g == 1) ? v : 0.f;
                s2 += (g == 2) ? v : 0.f;
                s3 += (g == 3) ? v : 0.f;
            }
        } else {
#pragma unroll
            for (int j = 0; j < 16; ++j) {
                int e = (j * 256 + t) * 2;
                int rl = e >> 7, cl = e & 127;
                int grow = m0 + half * 64 + rl;
                int gcol = n0 + cl;
                float v0 = epi[rl * 132 + cl];
                float v1 = epi[rl * 132 + cl + 1];
                *(uint*)&Cb[(size_t)grow * Nc + gcol] = (uint)f2bf(v0) | ((uint)f2bf(v1) << 16);
            }
        }
        __syncthreads();
    }
    if (OUT == 2) {
        if (rg == 1) {
            epi[colR * 4 + 0] = s0; epi[colR * 4 + 1] = s1;
            epi[colR * 4 + 2] = s2; epi[colR * 4 + 3] = s3;
        }
        __syncthreads();
        if (rg == 0) {
            s0 += epi[colR * 4 + 0]; s1 += epi[colR * 4 + 1];
            s2 += epi[colR * 4 + 2]; s3 += epi[colR * 4 + 3];
            int gcol = n0 + colR;
            if (gcol < Nc) {
                atomicAdd(&gsum[0 * Nc + gcol], s0);
                atomicAdd(&gsum[1 * Nc + gcol], s1);
                atomicAdd(&gsum[2 * Nc + gcol], s2);
                atomicAdd(&gsum[3 * Nc + gcol], s3);
            }
        }
        // ---- last-block ticket: 800-element divide (counts precomputed in scanA) ----
        __threadfence();
        __syncthreads();
        if (t == 0) lastFlag = (atomicAdd(donecnt, 1) == (int)gridDim.x - 1);
        __syncthreads();
        if (lastFlag) {
            __threadfence();
            for (int j = t; j < 800; j += 256) {
                int g = j / 200, col = j % 200;
                int c = atomicAdd(&gcnt[g], 0);               // coherent read
                float s = atomicAdd(&gsum[(size_t)g * Nc + col], 0.0f);  // coherent read
                outF[j] = (c > 0) ? s / (float)c : 0.0f;
            }
        }
    }
}

// ---------------- launch ----------------

extern "C" void kernel_launch(void* const* d_in, const int* in_sizes, int n_in,
                              void* d_out, int out_size, void* d_ws, size_t ws_size,
                              hipStream_t stream) {
    const float* x  = (const float*)d_in[0];
    const float* nf = (const float*)d_in[1];
    const int* ei   = (const int*)d_in[2];
    const float* W1 = (const float*)d_in[3];
    const float* b1 = (const float*)d_in[4];
    const float* W2 = (const float*)d_in[5];
    const float* b2 = (const float*)d_in[6];
    const float* W3 = (const float*)d_in[7];
    const float* b3 = (const float*)d_in[8];
    const float* W4 = (const float*)d_in[9];
    const float* b4 = (const float*)d_in[10];
    float* out = (float*)d_out;

    const int NN = in_sizes[0] / 100;  // 50000
    const int E  = in_sizes[2] / 2;    // 800000
    const int MPAD = ((NN + 127) / 128) * 128;  // 50048
    const int NB = (NN + 255) / 256;   // scan blocks (196 <= 256)
    const int PB = (NN + 3) / 4;       // prep blocks
    const int EB = (E + 255) / 256;    // deg/fill blocks
    const int TB = 1024;               // weight-split blocks
    const int* src = ei;
    const int* dst = ei + E;

    char* p = (char*)d_ws;
    auto alloc = [&](size_t bytes) -> char* {
        char* r = p;
        p += (bytes + 255) & ~(size_t)255;
        return r;
    };
    char* zz = p;
    int*   deg  = (int*)alloc((size_t)NN * 4);
    int*   cur  = (int*)alloc((size_t)NN * 4);
    float* gsum = (float*)alloc(800 * 4);
    int*   gcnt = (int*)alloc(256);    // gcnt[4] + donecnt
    size_t zz_bytes = (size_t)(p - zz);
    int*   donecnt = gcnt + 4;
    float* dinv = (float*)alloc((size_t)NN * 4);
    int*   offs = (int*)alloc((size_t)NN * 4);   // block-local prefix (scanA)
    int*   goffs = (int*)alloc((size_t)NN * 4);  // global prefix (fill)
    int*   bsum = (int*)alloc(1024);
    int*   gid  = (int*)alloc((size_t)NN * 4);
    uint2* epk  = (uint2*)alloc((size_t)E * 8);
    ushort* WT1h = (ushort*)alloc((size_t)512 * 128 * 2);
    ushort* WT1l = (ushort*)alloc((size_t)512 * 128 * 2);
    ushort* WT2h = (ushort*)alloc((size_t)256 * 512 * 2);
    ushort* WT2l = (ushort*)alloc((size_t)256 * 512 * 2);
    ushort* WT3h = (ushort*)alloc((size_t)128 * 256 * 2);
    ushort* WT3l = (ushort*)alloc((size_t)128 * 256 * 2);
    ushort* WT4h = (ushort*)alloc((size_t)256 * 128 * 2);
    ushort* WT4l = (ushort*)alloc((size_t)256 * 128 * 2);
    ushort* xb = (ushort*)alloc((size_t)NN * 128 * 2);
    ushort* P1 = (ushort*)alloc((size_t)MPAD * 128 * 2);
    ushort* H1 = (ushort*)alloc((size_t)MPAD * 512 * 2);
    ushort* T2 = (ushort*)alloc((size_t)MPAD * 256 * 2);
    ushort* H2 = (ushort*)alloc((size_t)MPAD * 256 * 2);
    ushort* T3 = (ushort*)alloc((size_t)MPAD * 128 * 2);
    ushort* H3 = (ushort*)alloc((size_t)MPAD * 128 * 2);
    ushort* P4 = (ushort*)alloc((size_t)MPAD * 128 * 2);

    hipMemsetAsync(zz, 0, zz_bytes, stream);

    k_init<<<PB + EB + TB, 256, 0, stream>>>(
        (const uint*)x, (const uint*)nf, xb, gid, NN, dst, E, deg,
        W1, W2, W3, W4, WT1h, WT1l, WT2h, WT2l, WT3h, WT3l, WT4h, WT4l, PB, EB);
    k_scanA<<<NB, 256, 0, stream>>>(deg, offs, bsum, dinv, gid, gcnt, NN);
    k_fill<<<EB, 256, 0, stream>>>(src, dst, E, dinv, offs, bsum, cur, epk, NN, NB, goffs);

    int aggBlocks = MPAD / 4;  // one wave per node incl. pad rows
    int mB = MPAD / 128;

    // P1 = agg(xb) -> bf16 [MPAD,128]
    k_aggs<128, false><<<aggBlocks, 256, 0, stream>>>(xb, P1, dinv, goffs, deg, epk, nullptr, NN, MPAD);
    // H1 = relu(P1 @ W1 + b1) -> bf16 [MPAD,512]
    k_gemm<true, 1><<<mB * 4, 256, 0, stream>>>(P1, WT1h, WT1l, b1, H1, 512, 128, 4, nullptr, nullptr, 0, nullptr, nullptr, nullptr);
    // T2 = H1 @ W2 -> bf16 [MPAD,256]
    k_gemm<false, 1><<<mB * 2, 256, 0, stream>>>(H1, WT2h, WT2l, nullptr, T2, 256, 512, 2, nullptr, nullptr, 0, nullptr, nullptr, nullptr);
    // H2 = relu(agg(T2) + b2) -> bf16 [MPAD,256]
    k_aggs<256, true><<<aggBlocks, 256, 0, stream>>>(T2, H2, dinv, goffs, deg, epk, b2, NN, MPAD);
    // T3 = H2 @ W3 -> bf16 [MPAD,128]
    k_gemm<false, 1><<<mB * 1, 256, 0, stream>>>(H2, WT3h, WT3l, nullptr, T3, 128, 256, 1, nullptr, nullptr, 0, nullptr, nullptr, nullptr);
    // H3 = relu(agg(T3) + b3) -> bf16 [MPAD,128]
    k_aggs<128, true><<<aggBlocks, 256, 0, stream>>>(T3, H3, dinv, goffs, deg, epk, b3, NN, MPAD);
    // P4 = agg(H3) -> bf16 [MPAD,128]
    k_aggs<128, false><<<aggBlocks, 256, 0, stream>>>(H3, P4, dinv, goffs, deg, epk, nullptr, NN, MPAD);
    // relu(P4 @ W4 + b4) -> group reduction + fused final divide (last-block ticket)
    k_gemm<true, 2><<<mB * 2, 256, 0, stream>>>(P4, WT4h, WT4l, b4, nullptr, 200, 128, 2, gid, gsum, NN, gcnt, out, donecnt);
}

// Round 18
// 458.718 us; speedup vs baseline: 1.0622x; 1.0622x over previous
//
#include <hip/hip_runtime.h>
#include <stdint.h>

typedef __attribute__((ext_vector_type(8))) short bf16x8;
typedef __attribute__((ext_vector_type(4))) float f32x4;

__device__ __forceinline__ float bf2f(ushort h) {
    union { uint u; float f; } v; v.u = ((uint)h) << 16; return v.f;
}
__device__ __forceinline__ ushort f2bf(float f) {
    union { float f; uint u; } v; v.f = f;
    uint u = v.u;
    return (ushort)((u + 0x7fffu + ((u >> 16) & 1u)) >> 16);
}

// async global->LDS, 16B per lane; LDS dest = wave-uniform base + lane*16
__device__ __forceinline__ void gll(const ushort* g, ushort* l) {
    __builtin_amdgcn_global_load_lds(
        (const __attribute__((address_space(1))) void*)g,
        (__attribute__((address_space(3))) void*)l, 16, 0, 0);
}

template <int VEC>
__device__ __forceinline__ void ldbf(const ushort* p, float* v) {
    if constexpr (VEC == 4) {
        uint2 u = *(const uint2*)p;
        v[0] = bf2f((ushort)(u.x & 0xffffu));
        v[1] = bf2f((ushort)(u.x >> 16));
        v[2] = bf2f((ushort)(u.y & 0xffffu));
        v[3] = bf2f((ushort)(u.y >> 16));
    } else {  // VEC == 8
        uint4 u = *(const uint4*)p;
        v[0] = bf2f((ushort)(u.x & 0xffffu));
        v[1] = bf2f((ushort)(u.x >> 16));
        v[2] = bf2f((ushort)(u.y & 0xffffu));
        v[3] = bf2f((ushort)(u.y >> 16));
        v[4] = bf2f((ushort)(u.z & 0xffffu));
        v[5] = bf2f((ushort)(u.z >> 16));
        v[6] = bf2f((ushort)(u.w & 0xffffu));
        v[7] = bf2f((ushort)(u.w >> 16));
    }
}

// ---------------- merged init: prep (classify + x->bf16) | deg | weight split ----------------
// NOTE: no gcnt atomics here (r12: 12.5k blocks on one cacheline cost +100us).

__device__ __forceinline__ void tr2_one(const float* __restrict__ W,
                                        ushort* __restrict__ WTh, ushort* __restrict__ WTl,
                                        int K, int Nc, int KP, int idx) {
    int n = idx / KP, k = idx % KP;
    float w = (n < Nc && k < K) ? W[(size_t)k * Nc + n] : 0.0f;
    ushort hi = f2bf(w);
    ushort lo = f2bf(w - bf2f(hi));
    WTh[idx] = hi;
    WTl[idx] = lo;
}

__global__ void k_init(const uint* __restrict__ xu, const uint* __restrict__ nfu,
                       ushort* __restrict__ xb, int* __restrict__ gid, int NN,
                       const int* __restrict__ dst, int E, int* __restrict__ deg,
                       const float* __restrict__ W1, const float* __restrict__ W2,
                       const float* __restrict__ W3, const float* __restrict__ W4,
                       ushort* __restrict__ WT1h, ushort* __restrict__ WT1l,
                       ushort* __restrict__ WT2h, ushort* __restrict__ WT2l,
                       ushort* __restrict__ WT3h, ushort* __restrict__ WT3l,
                       ushort* __restrict__ WT4h, ushort* __restrict__ WT4l,
                       int PB, int EB) {
    int b = blockIdx.x;
    if (b < PB) {
        int wid = b * 4 + (threadIdx.x >> 6);
        int lane = threadIdx.x & 63;
        if (wid >= NN) return;
        int c0 = lane * 2;
        uint w = 0u;
        int m0 = 1, m1 = 1, m2 = 1;
        if (c0 < 100) {
            uint2 xv = *(const uint2*)&xu[(size_t)wid * 100 + c0];
            uint2 a = *(const uint2*)&nfu[c0];
            uint2 bb = *(const uint2*)&nfu[100 + c0];
            uint2 c = *(const uint2*)&nfu[200 + c0];
            m0 = (xv.x == a.x) & (xv.y == a.y);
            m1 = (xv.x == bb.x) & (xv.y == bb.y);
            m2 = (xv.x == c.x) & (xv.y == c.y);
            w = (uint)f2bf(__uint_as_float(xv.x)) | ((uint)f2bf(__uint_as_float(xv.y)) << 16);
        }
        int e0 = __all(m0), e1 = __all(m1), e2 = __all(m2);
        *(uint*)&xb[(size_t)wid * 128 + c0] = w;
        if (lane == 0) gid[wid] = e0 ? 0 : (e1 ? 3 : (e2 ? 1 : 2));
    } else if (b < PB + EB) {
        int e = (b - PB) * 256 + threadIdx.x;
        if (e < E) atomicAdd(&deg[dst[e]], 1);
    } else {
        int idx = (b - PB - EB) * 256 + threadIdx.x;
        if (idx < 65536) tr2_one(W1, WT1h, WT1l, 100, 512, 128, idx);
        else if (idx < 196608) tr2_one(W2, WT2h, WT2l, 512, 256, 512, idx - 65536);
        else if (idx < 229376) tr2_one(W3, WT3h, WT3l, 256, 128, 256, idx - 196608);
        else if (idx < 262144) tr2_one(W4, WT4h, WT4l, 128, 200, 128, idx - 229376);
    }
}

// ---------------- scanA: block-local prefix + dinv + group counts ----------------
// (196 blocks x 4 gcnt atomics — measured free in r17, unlike 12.5k blocks in r12)

__global__ void k_scanA(const int* __restrict__ deg, int* __restrict__ offs,
                        int* __restrict__ bsum, float* __restrict__ dinv,
                        const int* __restrict__ gid, int* __restrict__ gcnt, int NN) {
    __shared__ int lds[256];
    __shared__ int cnt4[4];
    int t = threadIdx.x;
    if (t < 4) cnt4[t] = 0;
    int i = blockIdx.x * 256 + t;
    int v = (i < NN) ? deg[i] : 0;
    if (i < NN) dinv[i] = 1.0f / sqrtf((float)(v + 1));  // +1 self loop
    lds[t] = v;
    __syncthreads();
    if (i < NN) atomicAdd(&cnt4[gid[i]], 1);
    for (int d = 1; d < 256; d <<= 1) {
        int u = (t >= d) ? lds[t - d] : 0;
        __syncthreads();
        lds[t] += u;
        __syncthreads();
    }
    if (i < NN) offs[i] = lds[t] - v;  // block-local exclusive
    if (t == 255) bsum[blockIdx.x] = lds[255];
    __syncthreads();
    if (t < 4 && cnt4[t]) atomicAdd(&gcnt[t], cnt4[t]);
}

// ---------------- fill: recompute bsum prefix in-block (no scanB launch) ----------------

__global__ void k_fill(const int* __restrict__ src, const int* __restrict__ dst, int E,
                       const float* __restrict__ dinv, const int* __restrict__ offs,
                       const int* __restrict__ bsum,
                       int* __restrict__ cur, uint2* __restrict__ epk, int NN, int NB,
                       int* __restrict__ goffs) {
    __shared__ int sex[256];
    int t = threadIdx.x;
    int v = (t < NB) ? bsum[t] : 0;
    sex[t] = v;
    __syncthreads();
    for (int d = 1; d < 256; d <<= 1) {
        int u = (t >= d) ? sex[t - d] : 0;
        __syncthreads();
        sex[t] += u;
        __syncthreads();
    }
    int incl = sex[t];
    __syncthreads();
    sex[t] = incl - v;  // exclusive prefix of bsum
    __syncthreads();
    int i = blockIdx.x * 256 + t;
    if (i < NN) goffs[i] = offs[i] + sex[i >> 8];
    if (i >= E) return;
    int s = src[i], d = dst[i];
    int p = offs[d] + sex[d >> 8] + atomicAdd(&cur[d], 1);
    epk[p] = make_uint2((uint)s, __float_as_uint(dinv[s] * dinv[d]));
}

// ---------------- aggregation: wave per node, edge-split across half-waves ----------------

template <int D, bool BR>
__global__ void k_aggs(const ushort* __restrict__ H, ushort* __restrict__ outb,
                       const float* __restrict__ dinv, const int* __restrict__ offs,
                       const int* __restrict__ deg, const uint2* __restrict__ epk,
                       const float* __restrict__ bias, int NN, int NNpad) {
    constexpr int VEC = D / 32;  // cols per lane (half-wave covers the row)
    int wid = (int)((blockIdx.x * blockDim.x + threadIdx.x) >> 6);
    int lane = threadIdx.x & 63;
    int half = lane >> 5, sl = lane & 31;
    if (wid >= NNpad) return;
    int c0 = sl * VEC;
    ushort* op = outb + (size_t)wid * D + c0;
    if (wid >= NN) {  // zero pad rows
        if (half == 0) {
            if (VEC == 4) *(uint2*)op = make_uint2(0u, 0u);
            else { uint4 z; z.x = z.y = z.z = z.w = 0u; *(uint4*)op = z; }
        }
        return;
    }
    float acc[VEC];
#pragma unroll
    for (int j = 0; j < VEC; ++j) acc[j] = 0.0f;
    int beg = offs[wid], d = deg[wid];
    if (half == 0) {  // self-loop term on half 0
        float t0[VEC];
        ldbf<VEC>(H + (size_t)wid * D + c0, t0);
        float di = dinv[wid];
        float sw = di * di;
#pragma unroll
        for (int j = 0; j < VEC; ++j) acc[j] = sw * t0[j];
    }
    int d0 = (d + 1) >> 1;
    int e = beg + half * d0;
    int end = e + (half ? (d - d0) : d0);
    for (; e + 3 < end; e += 4) {
        uint2 q0 = epk[e], q1 = epk[e + 1], q2 = epk[e + 2], q3 = epk[e + 3];
        float t0[VEC], t1[VEC], t2[VEC], t3[VEC];
        ldbf<VEC>(H + (size_t)q0.x * D + c0, t0);
        ldbf<VEC>(H + (size_t)q1.x * D + c0, t1);
        ldbf<VEC>(H + (size_t)q2.x * D + c0, t2);
        ldbf<VEC>(H + (size_t)q3.x * D + c0, t3);
        float w0 = __uint_as_float(q0.y), w1 = __uint_as_float(q1.y);
        float w2 = __uint_as_float(q2.y), w3 = __uint_as_float(q3.y);
#pragma unroll
        for (int j = 0; j < VEC; ++j) acc[j] += w0 * t0[j];
#pragma unroll
        for (int j = 0; j < VEC; ++j) acc[j] += w1 * t1[j];
#pragma unroll
        for (int j = 0; j < VEC; ++j) acc[j] += w2 * t2[j];
#pragma unroll
        for (int j = 0; j < VEC; ++j) acc[j] += w3 * t3[j];
    }
    for (; e < end; ++e) {
        uint2 q0 = epk[e];
        float t0[VEC];
        ldbf<VEC>(H + (size_t)q0.x * D + c0, t0);
        float w0 = __uint_as_float(q0.y);
#pragma unroll
        for (int j = 0; j < VEC; ++j) acc[j] += w0 * t0[j];
    }
#pragma unroll
    for (int j = 0; j < VEC; ++j) acc[j] += __shfl_xor(acc[j], 32);
    if (half == 0) {
        ushort r[VEC];
#pragma unroll
        for (int j = 0; j < VEC; ++j) {
            float v = acc[j];
            if (BR) v = fmaxf(v + bias[c0 + j], 0.0f);
            r[j] = f2bf(v);
        }
        if (VEC == 4) {
            uint2 w;
            w.x = (uint)r[0] | ((uint)r[1] << 16);
            w.y = (uint)r[2] | ((uint)r[3] << 16);
            *(uint2*)op = w;
        } else {
            uint4 w;
            w.x = (uint)r[0] | ((uint)r[1] << 16);
            w.y = (uint)r[2] | ((uint)r[3] << 16);
            w.z = (uint)r[4] | ((uint)r[5] << 16);
            w.w = (uint)r[6] | ((uint)r[7] << 16);
            *(uint4*)op = w;
        }
    }
}

// ---------------- MFMA GEMM: A bf16 single plane, W hi/lo split (2-term) ----------------
// Block tile 128x128, 4 waves (64x64). OUT: 1 = bf16 store,
// 2 = fused per-group row reduction into gsum[4][Nc] (no C store, NO ticket —
// r11/r17: intra-kernel device-scope sync costs more than a kernel boundary).

template <bool BR, int OUT>
__global__ __launch_bounds__(256) void k_gemm(
        const ushort* __restrict__ A,
        const ushort* __restrict__ Bh, const ushort* __restrict__ Bl,
        const float* __restrict__ bias,
        ushort* __restrict__ Cb,
        int Nc, int K, int tNb,
        const int* __restrict__ gid, float* __restrict__ gsum, int NN) {
    __shared__ union {
        ushort st[3][128 * 32];
        float epi[64 * 132];
    } sm;
    __shared__ int gcode[64];
    int bm = blockIdx.x / tNb, bn = blockIdx.x % tNb;
    int m0 = bm * 128, n0 = bn * 128;
    int wv = threadIdx.x >> 6, lane = threadIdx.x & 63;
    int l15 = lane & 15, quad = lane >> 4;
    const ushort* gsrc;
    ushort* ldst;
    int ng;
    if (wv == 0)      { gsrc = A  + (size_t)m0 * K;        ldst = sm.st[0];        ng = 4; }
    else if (wv == 1) { gsrc = A  + (size_t)(m0 + 64) * K; ldst = sm.st[0] + 2048; ng = 4; }
    else if (wv == 2) { gsrc = Bh + (size_t)n0 * K;        ldst = sm.st[1];        ng = 8; }
    else              { gsrc = Bl + (size_t)n0 * K;        ldst = sm.st[2];        ng = 8; }
    const ushort* gBase = gsrc + (size_t)(lane >> 2) * K + (lane & 3) * 8;
    int wm = (wv >> 1) * 64, wn = (wv & 1) * 64;
    const ushort* sA_ = sm.st[0];
    const ushort* sBh_ = sm.st[1];
    const ushort* sBl_ = sm.st[2];
    f32x4 acc[4][4] = {};
    for (int k0 = 0; k0 < K; k0 += 32) {
        for (int i = 0; i < ng; ++i)
            gll(gBase + (size_t)(16 * i) * K + k0, ldst + i * 512);
        __syncthreads();
        bf16x8 Af[4], Bfh[4], Bfl[4];
#pragma unroll
        for (int i = 0; i < 4; ++i) {
            int ra = (wm + 16 * i + l15) * 32 + quad * 8;
            int rb = (wn + 16 * i + l15) * 32 + quad * 8;
            Af[i]  = *(const bf16x8*)(sA_ + ra);
            Bfh[i] = *(const bf16x8*)(sBh_ + rb);
            Bfl[i] = *(const bf16x8*)(sBl_ + rb);
        }
#pragma unroll
        for (int mi = 0; mi < 4; ++mi)
#pragma unroll
            for (int ni = 0; ni < 4; ++ni) {
                acc[mi][ni] = __builtin_amdgcn_mfma_f32_16x16x32_bf16(Af[mi], Bfh[ni], acc[mi][ni], 0, 0, 0);
                acc[mi][ni] = __builtin_amdgcn_mfma_f32_16x16x32_bf16(Af[mi], Bfl[ni], acc[mi][ni], 0, 0, 0);
            }
        __syncthreads();
    }
    float bia[4] = {0.f, 0.f, 0.f, 0.f};
    if (BR) {
#pragma unroll
        for (int ni = 0; ni < 4; ++ni) {
            int col = n0 + wn + 16 * ni + l15;
            if (col < Nc) bia[ni] = bias[col];
        }
    }
    float* epi = sm.epi;
    int t = threadIdx.x;
    float s0 = 0.f, s1 = 0.f, s2 = 0.f, s3 = 0.f;  // OUT==2 per-group sums
    int colR = t & 127, rg = t >> 7;
    for (int half = 0; half < 2; ++half) {
        if ((wv >> 1) == half) {
#pragma unroll
            for (int mi = 0; mi < 4; ++mi)
#pragma unroll
                for (int r = 0; r < 4; ++r) {
                    int rl = mi * 16 + quad * 4 + r;
#pragma unroll
                    for (int ni = 0; ni < 4; ++ni) {
                        float v = acc[mi][ni][r];
                        if (BR) v = fmaxf(v + bia[ni], 0.0f);
                        epi[rl * 132 + wn + ni * 16 + l15] = v;
                    }
                }
        }
        if (OUT == 2 && t < 64) {
            int grow = m0 + half * 64 + t;
            gcode[t] = (grow < NN) ? gid[grow] : -1;
        }
        __syncthreads();
        if (OUT == 2) {
#pragma unroll 4
            for (int r = 0; r < 32; ++r) {
                int row = rg * 32 + r;
                int g = gcode[row];
                float v = epi[row * 132 + colR];
                s0 += (g == 0) ? v : 0.f;
                s1 += (g == 1) ? v : 0.f;
                s2 += (g == 2) ? v : 0.f;
                s3 += (g == 3) ? v : 0.f;
            }
        } else {
#pragma unroll
            for (int j = 0; j < 16; ++j) {
                int e = (j * 256 + t) * 2;
                int rl = e >> 7, cl = e & 127;
                int grow = m0 + half * 64 + rl;
                int gcol = n0 + cl;
                float v0 = epi[rl * 132 + cl];
                float v1 = epi[rl * 132 + cl + 1];
                *(uint*)&Cb[(size_t)grow * Nc + gcol] = (uint)f2bf(v0) | ((uint)f2bf(v1) << 16);
            }
        }
        __syncthreads();
    }
    if (OUT == 2) {
        if (rg == 1) {
            epi[colR * 4 + 0] = s0; epi[colR * 4 + 1] = s1;
            epi[colR * 4 + 2] = s2; epi[colR * 4 + 3] = s3;
        }
        __syncthreads();
        if (rg == 0) {
            s0 += epi[colR * 4 + 0]; s1 += epi[colR * 4 + 1];
            s2 += epi[colR * 4 + 2]; s3 += epi[colR * 4 + 3];
            int gcol = n0 + colR;
            if (gcol < Nc) {
                atomicAdd(&gsum[0 * Nc + gcol], s0);
                atomicAdd(&gsum[1 * Nc + gcol], s1);
                atomicAdd(&gsum[2 * Nc + gcol], s2);
                atomicAdd(&gsum[3 * Nc + gcol], s3);
            }
        }
    }
}

// ---------------- final: divide by precomputed group counts (no gid scan) ----------------

__global__ void k_final(const float* __restrict__ gsum, const int* __restrict__ gcnt,
                        float* __restrict__ out) {
    int j = blockIdx.x * blockDim.x + threadIdx.x;
    if (j >= 800) return;
    int c = gcnt[j / 200];
    out[j] = (c > 0) ? gsum[j] / (float)c : 0.0f;
}

// ---------------- launch ----------------

extern "C" void kernel_launch(void* const* d_in, const int* in_sizes, int n_in,
                              void* d_out, int out_size, void* d_ws, size_t ws_size,
                              hipStream_t stream) {
    const float* x  = (const float*)d_in[0];
    const float* nf = (const float*)d_in[1];
    const int* ei   = (const int*)d_in[2];
    const float* W1 = (const float*)d_in[3];
    const float* b1 = (const float*)d_in[4];
    const float* W2 = (const float*)d_in[5];
    const float* b2 = (const float*)d_in[6];
    const float* W3 = (const float*)d_in[7];
    const float* b3 = (const float*)d_in[8];
    const float* W4 = (const float*)d_in[9];
    const float* b4 = (const float*)d_in[10];
    float* out = (float*)d_out;

    const int NN = in_sizes[0] / 100;  // 50000
    const int E  = in_sizes[2] / 2;    // 800000
    const int MPAD = ((NN + 127) / 128) * 128;  // 50048
    const int NB = (NN + 255) / 256;   // scan blocks (196 <= 256)
    const int PB = (NN + 3) / 4;       // prep blocks
    const int EB = (E + 255) / 256;    // deg/fill blocks
    const int TB = 1024;               // weight-split blocks
    const int* src = ei;
    const int* dst = ei + E;

    char* p = (char*)d_ws;
    auto alloc = [&](size_t bytes) -> char* {
        char* r = p;
        p += (bytes + 255) & ~(size_t)255;
        return r;
    };
    char* zz = p;
    int*   deg  = (int*)alloc((size_t)NN * 4);
    int*   cur  = (int*)alloc((size_t)NN * 4);
    float* gsum = (float*)alloc(800 * 4);
    int*   gcnt = (int*)alloc(256);
    size_t zz_bytes = (size_t)(p - zz);
    float* dinv = (float*)alloc((size_t)NN * 4);
    int*   offs = (int*)alloc((size_t)NN * 4);   // block-local prefix (scanA)
    int*   goffs = (int*)alloc((size_t)NN * 4);  // global prefix (fill)
    int*   bsum = (int*)alloc(1024);
    int*   gid  = (int*)alloc((size_t)NN * 4);
    uint2* epk  = (uint2*)alloc((size_t)E * 8);
    ushort* WT1h = (ushort*)alloc((size_t)512 * 128 * 2);
    ushort* WT1l = (ushort*)alloc((size_t)512 * 128 * 2);
    ushort* WT2h = (ushort*)alloc((size_t)256 * 512 * 2);
    ushort* WT2l = (ushort*)alloc((size_t)256 * 512 * 2);
    ushort* WT3h = (ushort*)alloc((size_t)128 * 256 * 2);
    ushort* WT3l = (ushort*)alloc((size_t)128 * 256 * 2);
    ushort* WT4h = (ushort*)alloc((size_t)256 * 128 * 2);
    ushort* WT4l = (ushort*)alloc((size_t)256 * 128 * 2);
    ushort* xb = (ushort*)alloc((size_t)NN * 128 * 2);
    ushort* P1 = (ushort*)alloc((size_t)MPAD * 128 * 2);
    ushort* H1 = (ushort*)alloc((size_t)MPAD * 512 * 2);
    ushort* T2 = (ushort*)alloc((size_t)MPAD * 256 * 2);
    ushort* H2 = (ushort*)alloc((size_t)MPAD * 256 * 2);
    ushort* T3 = (ushort*)alloc((size_t)MPAD * 128 * 2);
    ushort* H3 = (ushort*)alloc((size_t)MPAD * 128 * 2);
    ushort* P4 = (ushort*)alloc((size_t)MPAD * 128 * 2);

    hipMemsetAsync(zz, 0, zz_bytes, stream);

    k_init<<<PB + EB + TB, 256, 0, stream>>>(
        (const uint*)x, (const uint*)nf, xb, gid, NN, dst, E, deg,
        W1, W2, W3, W4, WT1h, WT1l, WT2h, WT2l, WT3h, WT3l, WT4h, WT4l, PB, EB);
    k_scanA<<<NB, 256, 0, stream>>>(deg, offs, bsum, dinv, gid, gcnt, NN);
    k_fill<<<EB, 256, 0, stream>>>(src, dst, E, dinv, offs, bsum, cur, epk, NN, NB, goffs);

    int aggBlocks = MPAD / 4;  // one wave per node incl. pad rows
    int mB = MPAD / 128;

    // P1 = agg(xb) -> bf16 [MPAD,128]
    k_aggs<128, false><<<aggBlocks, 256, 0, stream>>>(xb, P1, dinv, goffs, deg, epk, nullptr, NN, MPAD);
    // H1 = relu(P1 @ W1 + b1) -> bf16 [MPAD,512]
    k_gemm<true, 1><<<mB * 4, 256, 0, stream>>>(P1, WT1h, WT1l, b1, H1, 512, 128, 4, nullptr, nullptr, 0);
    // T2 = H1 @ W2 -> bf16 [MPAD,256]
    k_gemm<false, 1><<<mB * 2, 256, 0, stream>>>(H1, WT2h, WT2l, nullptr, T2, 256, 512, 2, nullptr, nullptr, 0);
    // H2 = relu(agg(T2) + b2) -> bf16 [MPAD,256]
    k_aggs<256, true><<<aggBlocks, 256, 0, stream>>>(T2, H2, dinv, goffs, deg, epk, b2, NN, MPAD);
    // T3 = H2 @ W3 -> bf16 [MPAD,128]
    k_gemm<false, 1><<<mB * 1, 256, 0, stream>>>(H2, WT3h, WT3l, nullptr, T3, 128, 256, 1, nullptr, nullptr, 0);
    // H3 = relu(agg(T3) + b3) -> bf16 [MPAD,128]
    k_aggs<128, true><<<aggBlocks, 256, 0, stream>>>(T3, H3, dinv, goffs, deg, epk, b3, NN, MPAD);
    // P4 = agg(H3) -> bf16 [MPAD,128]
    k_aggs<128, false><<<aggBlocks, 256, 0, stream>>>(H3, P4, dinv, goffs, deg, epk, nullptr, NN, MPAD);
    // relu(P4 @ W4 + b4) -> per-group reduction into gsum (no H4 tensor)
    k_gemm<true, 2><<<mB * 2, 256, 0, stream>>>(P4, WT4h, WT4l, b4, nullptr, 200, 128, 2, gid, gsum, NN);

    k_final<<<4, 256, 0, stream>>>(gsum, gcnt, out);
}